// Round 1
// 647.601 us; speedup vs baseline: 1.0461x; 1.0461x over previous
//
#include <hip/hip_runtime.h>
#include <math.h>

// Problem constants (B, N, D_IN, D_STATE) = (32, 4096, 1024, 1024).
// softmax is shift-invariant, so the hidden@w_h + b term (constant over n)
// cancels exactly — only x@w_x matters.
#define N_SZ 4096
#define D_SZ 1024

typedef float f32x4 __attribute__((ext_vector_type(4)));

// Kernel 1: logits[row] = dot(x[row, 0:1024], w_x).
// One wave per 4 CONSECUTIVE rows per iteration: all 16 dwordx4 loads (16 KB)
// are issued before any arithmetic, so the memory queue never drains on the
// serial FMA+shuffle tail (previous version: 4 KB in flight, vmcnt(0) drain
// every row -> 1.6 TB/s). Four independent FMA/reduce chains pipeline the
// ds_bpermute latency. x is stream-once -> nontemporal loads. One float4
// store per 16 KB read.
__global__ __launch_bounds__(256) void logits_k(
    const float* __restrict__ x, const float* __restrict__ wx,
    float* __restrict__ out, int nrows)
{
    const int lane = threadIdx.x & 63;
    const int wid  = blockIdx.x * (blockDim.x >> 6) + (threadIdx.x >> 6);
    const int nw   = gridDim.x * (blockDim.x >> 6);

    const f32x4* w4 = (const f32x4*)wx;
    const f32x4 w0 = w4[lane];
    const f32x4 w1 = w4[64  + lane];
    const f32x4 w2 = w4[128 + lane];
    const f32x4 w3 = w4[192 + lane];

    // Wave wid handles rows [4*wid, 4*wid+4) each sweep; sweeps stride 4*nw.
    // nrows = 131072 is a multiple of 4*nw = 32768 -> exactly 4 sweeps, no tail.
    for (int base = wid * 4; base < nrows; base += nw * 4) {
        f32x4 a[4][4];
        #pragma unroll
        for (int r = 0; r < 4; ++r) {
            const f32x4* xr = (const f32x4*)(x + (size_t)(base + r) * D_SZ);
            a[r][0] = __builtin_nontemporal_load(xr + lane);
            a[r][1] = __builtin_nontemporal_load(xr + 64  + lane);
            a[r][2] = __builtin_nontemporal_load(xr + 128 + lane);
            a[r][3] = __builtin_nontemporal_load(xr + 192 + lane);
        }

        float s[4];
        #pragma unroll
        for (int r = 0; r < 4; ++r) {
            f32x4 acc = a[r][0] * w0;
            acc += a[r][1] * w1;
            acc += a[r][2] * w2;
            acc += a[r][3] * w3;
            s[r] = (acc[0] + acc[1]) + (acc[2] + acc[3]);
        }

        // 4 independent 6-step butterfly chains -> shuffle latency overlaps.
        #pragma unroll
        for (int off = 32; off > 0; off >>= 1) {
            #pragma unroll
            for (int r = 0; r < 4; ++r)
                s[r] += __shfl_down(s[r], off, 64);
        }

        if (lane == 0) {
            f32x4 o = { s[0], s[1], s[2], s[3] };
            *(f32x4*)(out + base) = o;   // rows consecutive -> one dwordx4 store
        }
    }
}

// Kernel 2: in-place softmax over N=4096 per batch row. One block (256 thr)
// per row; 16 logits/thread held in registers so the row is read once.
__global__ __launch_bounds__(256) void softmax_k(float* __restrict__ io)
{
    float* row = io + (size_t)blockIdx.x * N_SZ;
    const int tid  = threadIdx.x;
    const int lane = tid & 63;
    const int wv   = tid >> 6;
    __shared__ float sred[4];

    float v[16];
    float m = -INFINITY;
    #pragma unroll
    for (int j = 0; j < 16; ++j) {
        v[j] = row[tid + j * 256];
        m = fmaxf(m, v[j]);
    }
    #pragma unroll
    for (int off = 32; off > 0; off >>= 1)
        m = fmaxf(m, __shfl_down(m, off, 64));
    if (lane == 0) sred[wv] = m;
    __syncthreads();
    m = fmaxf(fmaxf(sred[0], sred[1]), fmaxf(sred[2], sred[3]));
    __syncthreads();   // sred about to be reused

    float s = 0.0f;
    #pragma unroll
    for (int j = 0; j < 16; ++j) {
        v[j] = expf(v[j] - m);
        s += v[j];
    }
    #pragma unroll
    for (int off = 32; off > 0; off >>= 1)
        s += __shfl_down(s, off, 64);
    if (lane == 0) sred[wv] = s;
    __syncthreads();
    s = sred[0] + sred[1] + sred[2] + sred[3];

    const float inv = 1.0f / s;
    #pragma unroll
    for (int j = 0; j < 16; ++j)
        row[tid + j * 256] = v[j] * inv;
}

extern "C" void kernel_launch(void* const* d_in, const int* in_sizes, int n_in,
                              void* d_out, int out_size, void* d_ws, size_t ws_size,
                              hipStream_t stream) {
    const float* x  = (const float*)d_in[0];   // fixed_inputs [32,4096,1024]
    const float* wx = (const float*)d_in[2];   // w_x [1024]
    // d_in[1] (hidden), d_in[3] (w_h), d_in[4] (b) cancel under softmax.
    float* out = (float*)d_out;                // [32,4096] fp32

    const int nrows = out_size;                // 131072 = B*N
    logits_k<<<2048, 256, 0, stream>>>(x, wx, out, nrows);
    softmax_k<<<nrows / N_SZ, 256, 0, stream>>>(out);
}